// Round 2
// baseline (623.797 us; speedup 1.0000x reference)
//
#include <hip/hip_runtime.h>
#include <hip/hip_bf16.h>
#include <math.h>
#include <stdint.h>

#define TPB 256
#define NCB 32   // clusters per agg block

// ---------------------------------------------------------------------------
// Sort stage 1: histogram of labels
// ---------------------------------------------------------------------------
__global__ __launch_bounds__(TPB) void hist_kernel(
    const int* __restrict__ labels, int* __restrict__ counts, int n)
{
    int i = blockIdx.x * TPB + threadIdx.x;
    if (i < n) atomicAdd(&counts[labels[i]], 1);
}

// ---------------------------------------------------------------------------
// Parallel scan over C bins, 3 kernels:
//   S1: per-256-bin block: local exclusive scan -> off, block total -> bsum
//   S2: one block scans bsum (<=256 blocks) -> exclusive bases; off[C]=n
//   S3: off[i] += base[block]; cursor[i] = off[i]
// ---------------------------------------------------------------------------
__global__ __launch_bounds__(256) void scan_local(
    const int* __restrict__ counts, int* __restrict__ off,
    int* __restrict__ bsum, int C)
{
    __shared__ int sh[256];
    int t = threadIdx.x;
    int i = blockIdx.x * 256 + t;
    int v = (i < C) ? counts[i] : 0;
    sh[t] = v;
    __syncthreads();
    for (int d = 1; d < 256; d <<= 1) {
        int u = (t >= d) ? sh[t - d] : 0;
        __syncthreads();
        sh[t] += u;
        __syncthreads();
    }
    if (i < C) off[i] = sh[t] - v;          // local exclusive prefix
    if (t == 255) bsum[blockIdx.x] = sh[255];
}

__global__ __launch_bounds__(256) void scan_base(
    int* __restrict__ bsum, int* __restrict__ off, int nb, int C)
{
    __shared__ int sh[256];
    int t = threadIdx.x;
    int v = (t < nb) ? bsum[t] : 0;
    sh[t] = v;
    __syncthreads();
    for (int d = 1; d < 256; d <<= 1) {
        int u = (t >= d) ? sh[t - d] : 0;
        __syncthreads();
        sh[t] += u;
        __syncthreads();
    }
    if (t < nb) bsum[t] = sh[t] - v;        // exclusive base per block
    if (t == 255) off[C] = sh[255];         // total == n
}

__global__ __launch_bounds__(256) void scan_apply(
    int* __restrict__ off, int* __restrict__ cursor,
    const int* __restrict__ bsum, int C)
{
    int i = blockIdx.x * 256 + threadIdx.x;
    if (i < C) {
        int v = off[i] + bsum[blockIdx.x];
        off[i] = v;
        cursor[i] = v;
    }
}

// ---------------------------------------------------------------------------
// Stage 1: per-point MLP. Claims sorted slot via cursor atomic and writes the
// gated bf16 64-vector row at the sorted position (128B = 1 cacheline).
// R1 change: __launch_bounds__(TPB, 4) -> VGPR budget 128 (was: compiler chose
// 36 VGPR and spilled ~80B/thread; WRITE_SIZE showed +156MB scratch traffic).
// Peak live set (h2[16]+h3[32]+gate+addr) ~64 regs fits the new budget.
// ---------------------------------------------------------------------------
__global__ __launch_bounds__(TPB, 4) void point_mlp_kernel(
    const float* __restrict__ pf, const int* __restrict__ labels,
    const float* __restrict__ centers, const float* __restrict__ points,
    const float* __restrict__ we0, const float* __restrict__ be0,
    const float* __restrict__ we1, const float* __restrict__ be1,
    const float* __restrict__ we2, const float* __restrict__ be2,
    const float* __restrict__ we3, const float* __restrict__ be3,
    const float* __restrict__ wa0, const float* __restrict__ ba0,
    const float* __restrict__ wa1, const float* __restrict__ ba1,
    int* __restrict__ cursor, unsigned short* __restrict__ tsort, int n)
{
    int i = blockIdx.x * TPB + threadIdx.x;
    if (i >= n) return;

    float x[11];
    const float4* pf4 = (const float4*)pf;
    float4 p0 = pf4[(size_t)i * 2 + 0];
    float4 p1 = pf4[(size_t)i * 2 + 1];
    x[0] = p0.x; x[1] = p0.y; x[2] = p0.z; x[3] = p0.w;
    x[4] = p1.x; x[5] = p1.y; x[6] = p1.z; x[7] = p1.w;

    int lbl = labels[i];
    x[8]  = centers[lbl * 3 + 0] - points[(size_t)i * 3 + 0];
    x[9]  = centers[lbl * 3 + 1] - points[(size_t)i * 3 + 1];
    x[10] = centers[lbl * 3 + 2] - points[(size_t)i * 3 + 2];

    // claim sorted slot early; latency overlaps the MLP compute below
    int pos = atomicAdd(&cursor[lbl], 1);

    // attention MLP: 11 -> 64 relu -> 1 sigmoid
    float s = ba1[0];
#pragma unroll
    for (int j = 0; j < 64; j++) {
        float aj = ba0[j];
#pragma unroll
        for (int k = 0; k < 11; k++) aj = fmaf(x[k], wa0[k * 64 + j], aj);
        aj = fmaxf(aj, 0.f);
        s = fmaf(aj, wa1[j], s);
    }
    float gate = 1.f / (1.f + __expf(-s));

    // edge MLP: 11 -> 8 -> 16 -> 32
    float h1[8];
#pragma unroll
    for (int j = 0; j < 8; j++) {
        float v = be0[j];
#pragma unroll
        for (int k = 0; k < 11; k++) v = fmaf(x[k], we0[k * 8 + j], v);
        h1[j] = fmaxf(v, 0.f);
    }
    float h2[16];
#pragma unroll
    for (int j = 0; j < 16; j++) {
        float v = be1[j];
#pragma unroll
        for (int k = 0; k < 8; k++) v = fmaf(h1[k], we1[k * 16 + j], v);
        h2[j] = fmaxf(v, 0.f);
    }
    float h3[32];
#pragma unroll
    for (int j = 0; j < 32; j++) {
        float v = be2[j];
#pragma unroll
        for (int k = 0; k < 16; k++) v = fmaf(h2[k], we2[k * 32 + j], v);
        h3[j] = fmaxf(v, 0.f);
    }

    // final layer 32 -> 64, relu, gate, pack bf16, store row at sorted pos
    uint4* dst = (uint4*)(tsort + (size_t)pos * 64);
#pragma unroll
    for (int g = 0; g < 8; g++) {
        unsigned int w[4];
#pragma unroll
        for (int q = 0; q < 4; q++) {
            unsigned int packed = 0;
#pragma unroll
            for (int h = 0; h < 2; h++) {
                int j = g * 8 + q * 2 + h;
                float v = be3[j];
#pragma unroll
                for (int k = 0; k < 32; k++) v = fmaf(h3[k], we3[k * 64 + j], v);
                v = fmaxf(v, 0.f) * gate;
                __hip_bfloat16 b = __float2bfloat16(v);
                unsigned short us = *(unsigned short*)&b;
                packed |= ((unsigned int)us) << (16 * h);
            }
            w[q] = packed;
        }
        dst[g] = make_uint4(w[0], w[1], w[2], w[3]);
    }
}

// ---------------------------------------------------------------------------
// Stage 2: aggregation (coalesced streaming over tsort) + output MLP.
// ---------------------------------------------------------------------------
__global__ __launch_bounds__(TPB) void agg_outmlp_kernel(
    const unsigned short* __restrict__ tsort,
    const int* __restrict__ off,
    const float* __restrict__ wo0, const float* __restrict__ bo0,
    const float* __restrict__ wo1, const float* __restrict__ bo1,
    float* __restrict__ out)
{
    __shared__ float s_agg[NCB * 64];    // 8 KB
    __shared__ float s_mid[NCB * 128];   // 16 KB
    int tid = threadIdx.x;
    int c0 = blockIdx.x * NCB;
    const unsigned int* t32 = (const unsigned int*)tsort;

    // phase A: aggregate
    {
        int l = tid & 63;
        int w = tid >> 6;
#define BF_LO(u) (__uint_as_float((u) << 16))
#define BF_HI(u) (__uint_as_float((u) & 0xffff0000u))
        for (int lc = w * 8; lc < w * 8 + 8; lc++) {
            int rb = off[c0 + lc];
            int re = off[c0 + lc + 1];
            float a0 = 0.f, a1 = 0.f;
            int r = rb;
            for (; r + 8 <= re; r += 8) {
                unsigned int u0 = t32[(size_t)(r + 0) * 32 + l];
                unsigned int u1 = t32[(size_t)(r + 2) * 32 + l];
                unsigned int u2 = t32[(size_t)(r + 4) * 32 + l];
                unsigned int u3 = t32[(size_t)(r + 6) * 32 + l];
                a0 += BF_LO(u0) + BF_LO(u1) + BF_LO(u2) + BF_LO(u3);
                a1 += BF_HI(u0) + BF_HI(u1) + BF_HI(u2) + BF_HI(u3);
            }
            for (; r + 2 <= re; r += 2) {
                unsigned int u = t32[(size_t)r * 32 + l];
                a0 += BF_LO(u);
                a1 += BF_HI(u);
            }
            if (r < re && l < 32) {
                unsigned int u = t32[(size_t)r * 32 + l];
                a0 += BF_LO(u);
                a1 += BF_HI(u);
            }
            float b0 = __shfl(a0, (l + 32) & 63, 64);
            float b1 = __shfl(a1, (l + 32) & 63, 64);
            if (l < 32) {
                float2 v;
                v.x = a0 + b0;
                v.y = a1 + b1;
                *(float2*)&s_agg[lc * 64 + 2 * l] = v;
            }
        }
#undef BF_LO
#undef BF_HI
    }
    __syncthreads();

    // phase B: mid[NCB][128] = relu(agg @ wo0 + bo0)
    {
        int j = tid & 127;
        int g = tid >> 7;
        float acc[16];
        float b = bo0[j];
#pragma unroll
        for (int c = 0; c < 16; c++) acc[c] = b;
        for (int k = 0; k < 64; k += 4) {
            float w0 = wo0[(k + 0) * 128 + j];
            float w1 = wo0[(k + 1) * 128 + j];
            float w2 = wo0[(k + 2) * 128 + j];
            float w3 = wo0[(k + 3) * 128 + j];
#pragma unroll
            for (int c = 0; c < 16; c++) {
                const float4 av = *(const float4*)&s_agg[(g * 16 + c) * 64 + k];
                acc[c] = fmaf(av.x, w0, acc[c]);
                acc[c] = fmaf(av.y, w1, acc[c]);
                acc[c] = fmaf(av.z, w2, acc[c]);
                acc[c] = fmaf(av.w, w3, acc[c]);
            }
        }
#pragma unroll
        for (int c = 0; c < 16; c++)
            s_mid[(g * 16 + c) * 128 + j] = fmaxf(acc[c], 0.f);
    }
    __syncthreads();

    // phase C: out[NCB][256] = relu(mid @ wo1 + bo1)
    {
        int m = tid;
        float acc[NCB];
        float b = bo1[m];
#pragma unroll
        for (int c = 0; c < NCB; c++) acc[c] = b;
        for (int j = 0; j < 128; j += 4) {
            float w0 = wo1[(j + 0) * 256 + m];
            float w1 = wo1[(j + 1) * 256 + m];
            float w2 = wo1[(j + 2) * 256 + m];
            float w3 = wo1[(j + 3) * 256 + m];
#pragma unroll
            for (int c = 0; c < NCB; c++) {
                const float4 mv = *(const float4*)&s_mid[c * 128 + j];
                acc[c] = fmaf(mv.x, w0, acc[c]);
                acc[c] = fmaf(mv.y, w1, acc[c]);
                acc[c] = fmaf(mv.z, w2, acc[c]);
                acc[c] = fmaf(mv.w, w3, acc[c]);
            }
        }
#pragma unroll
        for (int c = 0; c < NCB; c++)
            out[(size_t)(c0 + c) * 256 + m] = fmaxf(acc[c], 0.f);
    }
}

extern "C" void kernel_launch(void* const* d_in, const int* in_sizes, int n_in,
                              void* d_out, int out_size, void* d_ws, size_t ws_size,
                              hipStream_t stream)
{
    const float* pf      = (const float*)d_in[0];
    const int*   labels  = (const int*)d_in[1];
    const float* centers = (const float*)d_in[2];
    const float* points  = (const float*)d_in[3];
    const float* we0 = (const float*)d_in[4];
    const float* be0 = (const float*)d_in[5];
    const float* we1 = (const float*)d_in[6];
    const float* be1 = (const float*)d_in[7];
    const float* we2 = (const float*)d_in[8];
    const float* be2 = (const float*)d_in[9];
    const float* we3 = (const float*)d_in[10];
    const float* be3 = (const float*)d_in[11];
    const float* wa0 = (const float*)d_in[12];
    const float* ba0 = (const float*)d_in[13];
    const float* wa1 = (const float*)d_in[14];
    const float* ba1 = (const float*)d_in[15];
    const float* wo0 = (const float*)d_in[16];
    const float* bo0 = (const float*)d_in[17];
    const float* wo1 = (const float*)d_in[18];
    const float* bo1 = (const float*)d_in[19];
    float* out = (float*)d_out;

    int n = in_sizes[0] / 8;        // N points (2,000,000)
    int C = in_sizes[2] / 3;        // clusters (65,536)

    // workspace layout
    int* counts = (int*)d_ws;                   // C
    int* cursor = counts + C;                   // C
    int* off    = cursor + C;                   // C+1
    int* bsum   = off + C + 1;                  // <=256
    uintptr_t tb = ((uintptr_t)(bsum + 256) + 255) & ~(uintptr_t)255;
    unsigned short* tsort = (unsigned short*)tb; // n x 64 bf16, cluster-sorted

    hipMemsetAsync(counts, 0, (size_t)C * sizeof(int), stream);

    int pblocks = (n + TPB - 1) / TPB;
    int nb = (C + 255) / 256;                   // 256 scan blocks
    hist_kernel<<<pblocks, TPB, 0, stream>>>(labels, counts, n);
    scan_local<<<nb, 256, 0, stream>>>(counts, off, bsum, C);
    scan_base<<<1, 256, 0, stream>>>(bsum, off, nb, C);
    scan_apply<<<nb, 256, 0, stream>>>(off, cursor, bsum, C);

    point_mlp_kernel<<<pblocks, TPB, 0, stream>>>(
        pf, labels, centers, points,
        we0, be0, we1, be1, we2, be2, we3, be3,
        wa0, ba0, wa1, ba1, cursor, tsort, n);

    agg_outmlp_kernel<<<C / NCB, TPB, 0, stream>>>(
        tsort, off, wo0, bo0, wo1, bo1, out);
}

// Round 3
// 603.190 us; speedup vs baseline: 1.0342x; 1.0342x over previous
//
#include <hip/hip_runtime.h>
#include <hip/hip_bf16.h>
#include <math.h>
#include <stdint.h>

#define TPB 256
#define NCB 32   // clusters per agg block

// ---------------------------------------------------------------------------
// Sort stage 1: histogram of labels
// ---------------------------------------------------------------------------
__global__ __launch_bounds__(TPB) void hist_kernel(
    const int* __restrict__ labels, int* __restrict__ counts, int n)
{
    int i = blockIdx.x * TPB + threadIdx.x;
    if (i < n) atomicAdd(&counts[labels[i]], 1);
}

// ---------------------------------------------------------------------------
// Parallel scan over C bins, 3 kernels:
//   S1: per-256-bin block: local exclusive scan -> off, block total -> bsum
//   S2: one block scans bsum (<=256 blocks) -> exclusive bases; off[C]=n
//   S3: off[i] += base[block]; cursor[i] = off[i]
// ---------------------------------------------------------------------------
__global__ __launch_bounds__(256) void scan_local(
    const int* __restrict__ counts, int* __restrict__ off,
    int* __restrict__ bsum, int C)
{
    __shared__ int sh[256];
    int t = threadIdx.x;
    int i = blockIdx.x * 256 + t;
    int v = (i < C) ? counts[i] : 0;
    sh[t] = v;
    __syncthreads();
    for (int d = 1; d < 256; d <<= 1) {
        int u = (t >= d) ? sh[t - d] : 0;
        __syncthreads();
        sh[t] += u;
        __syncthreads();
    }
    if (i < C) off[i] = sh[t] - v;          // local exclusive prefix
    if (t == 255) bsum[blockIdx.x] = sh[255];
}

__global__ __launch_bounds__(256) void scan_base(
    int* __restrict__ bsum, int* __restrict__ off, int nb, int C)
{
    __shared__ int sh[256];
    int t = threadIdx.x;
    int v = (t < nb) ? bsum[t] : 0;
    sh[t] = v;
    __syncthreads();
    for (int d = 1; d < 256; d <<= 1) {
        int u = (t >= d) ? sh[t - d] : 0;
        __syncthreads();
        sh[t] += u;
        __syncthreads();
    }
    if (t < nb) bsum[t] = sh[t] - v;        // exclusive base per block
    if (t == 255) off[C] = sh[255];         // total == n
}

__global__ __launch_bounds__(256) void scan_apply(
    int* __restrict__ off, int* __restrict__ cursor,
    const int* __restrict__ bsum, int C)
{
    int i = blockIdx.x * 256 + threadIdx.x;
    if (i < C) {
        int v = off[i] + bsum[blockIdx.x];
        off[i] = v;
        cursor[i] = v;
    }
}

// ---------------------------------------------------------------------------
// Stage 1: per-point MLP. Claims sorted slot via cursor atomic and writes the
// gated bf16 64-vector row at the sorted position (128B = 1 cacheline).
// (R1 note: launch_bounds(TPB,4) had zero effect - VGPR stayed 36; kept as
// harmless. Do not re-theorize spilling without disasm evidence.)
// ---------------------------------------------------------------------------
__global__ __launch_bounds__(TPB, 4) void point_mlp_kernel(
    const float* __restrict__ pf, const int* __restrict__ labels,
    const float* __restrict__ centers, const float* __restrict__ points,
    const float* __restrict__ we0, const float* __restrict__ be0,
    const float* __restrict__ we1, const float* __restrict__ be1,
    const float* __restrict__ we2, const float* __restrict__ be2,
    const float* __restrict__ we3, const float* __restrict__ be3,
    const float* __restrict__ wa0, const float* __restrict__ ba0,
    const float* __restrict__ wa1, const float* __restrict__ ba1,
    int* __restrict__ cursor, unsigned short* __restrict__ tsort, int n)
{
    int i = blockIdx.x * TPB + threadIdx.x;
    if (i >= n) return;

    float x[11];
    const float4* pf4 = (const float4*)pf;
    float4 p0 = pf4[(size_t)i * 2 + 0];
    float4 p1 = pf4[(size_t)i * 2 + 1];
    x[0] = p0.x; x[1] = p0.y; x[2] = p0.z; x[3] = p0.w;
    x[4] = p1.x; x[5] = p1.y; x[6] = p1.z; x[7] = p1.w;

    int lbl = labels[i];
    x[8]  = centers[lbl * 3 + 0] - points[(size_t)i * 3 + 0];
    x[9]  = centers[lbl * 3 + 1] - points[(size_t)i * 3 + 1];
    x[10] = centers[lbl * 3 + 2] - points[(size_t)i * 3 + 2];

    // claim sorted slot early; latency overlaps the MLP compute below
    int pos = atomicAdd(&cursor[lbl], 1);

    // attention MLP: 11 -> 64 relu -> 1 sigmoid
    float s = ba1[0];
#pragma unroll
    for (int j = 0; j < 64; j++) {
        float aj = ba0[j];
#pragma unroll
        for (int k = 0; k < 11; k++) aj = fmaf(x[k], wa0[k * 64 + j], aj);
        aj = fmaxf(aj, 0.f);
        s = fmaf(aj, wa1[j], s);
    }
    float gate = 1.f / (1.f + __expf(-s));

    // edge MLP: 11 -> 8 -> 16 -> 32
    float h1[8];
#pragma unroll
    for (int j = 0; j < 8; j++) {
        float v = be0[j];
#pragma unroll
        for (int k = 0; k < 11; k++) v = fmaf(x[k], we0[k * 8 + j], v);
        h1[j] = fmaxf(v, 0.f);
    }
    float h2[16];
#pragma unroll
    for (int j = 0; j < 16; j++) {
        float v = be1[j];
#pragma unroll
        for (int k = 0; k < 8; k++) v = fmaf(h1[k], we1[k * 16 + j], v);
        h2[j] = fmaxf(v, 0.f);
    }
    float h3[32];
#pragma unroll
    for (int j = 0; j < 32; j++) {
        float v = be2[j];
#pragma unroll
        for (int k = 0; k < 16; k++) v = fmaf(h2[k], we2[k * 32 + j], v);
        h3[j] = fmaxf(v, 0.f);
    }

    // final layer 32 -> 64, relu, gate, pack bf16, store row at sorted pos
    uint4* dst = (uint4*)(tsort + (size_t)pos * 64);
#pragma unroll
    for (int g = 0; g < 8; g++) {
        unsigned int w[4];
#pragma unroll
        for (int q = 0; q < 4; q++) {
            unsigned int packed = 0;
#pragma unroll
            for (int h = 0; h < 2; h++) {
                int j = g * 8 + q * 2 + h;
                float v = be3[j];
#pragma unroll
                for (int k = 0; k < 32; k++) v = fmaf(h3[k], we3[k * 64 + j], v);
                v = fmaxf(v, 0.f) * gate;
                __hip_bfloat16 b = __float2bfloat16(v);
                unsigned short us = *(unsigned short*)&b;
                packed |= ((unsigned int)us) << (16 * h);
            }
            w[q] = packed;
        }
        dst[g] = make_uint4(w[0], w[1], w[2], w[3]);
    }
}

// ---------------------------------------------------------------------------
// Stage 2: aggregation + output MLP.
// R2 change (phase A only): uint4 loads - one wave-load covers 8 rows
// (8 lanes x 16B per row) instead of 2; unroll x2 -> 32B outstanding/lane;
// reduce across the 8 row-groups with 3x shfl_xor. Was ~1 TB/s (latency
// bound on 4B loads); target near-BW streaming of the 256MB tsort read.
// ---------------------------------------------------------------------------
__global__ __launch_bounds__(TPB) void agg_outmlp_kernel(
    const unsigned short* __restrict__ tsort,
    const int* __restrict__ off,
    const float* __restrict__ wo0, const float* __restrict__ bo0,
    const float* __restrict__ wo1, const float* __restrict__ bo1,
    float* __restrict__ out)
{
    __shared__ float s_agg[NCB * 64];    // 8 KB
    __shared__ float s_mid[NCB * 128];   // 16 KB
    int tid = threadIdx.x;
    int c0 = blockIdx.x * NCB;

    // phase A: aggregate
    {
        int lane  = tid & 63;
        int w     = tid >> 6;
        int rlane = lane >> 3;           // 0..7 : which row of the 8-row group
        int word  = lane & 7;            // 0..7 : uint4 index within 128B row
        const uint4* t128 = (const uint4*)tsort;   // one row = 8 x uint4
#define BF_LO(u) (__uint_as_float((u) << 16))
#define BF_HI(u) (__uint_as_float((u) & 0xffff0000u))
        for (int lc = w * 8; lc < w * 8 + 8; lc++) {
            int rb = off[c0 + lc];
            int re = off[c0 + lc + 1];
            float a[8];
#pragma unroll
            for (int q = 0; q < 8; q++) a[q] = 0.f;
            for (int r = rb; r < re; r += 16) {
                int r0 = r + rlane;
                int r1 = r + 8 + rlane;
                uint4 v0 = make_uint4(0u, 0u, 0u, 0u);
                uint4 v1 = make_uint4(0u, 0u, 0u, 0u);
                if (r0 < re) v0 = t128[(size_t)r0 * 8 + word];
                if (r1 < re) v1 = t128[(size_t)r1 * 8 + word];
                a[0] += BF_LO(v0.x) + BF_LO(v1.x);
                a[1] += BF_HI(v0.x) + BF_HI(v1.x);
                a[2] += BF_LO(v0.y) + BF_LO(v1.y);
                a[3] += BF_HI(v0.y) + BF_HI(v1.y);
                a[4] += BF_LO(v0.z) + BF_LO(v1.z);
                a[5] += BF_HI(v0.z) + BF_HI(v1.z);
                a[6] += BF_LO(v0.w) + BF_LO(v1.w);
                a[7] += BF_HI(v0.w) + BF_HI(v1.w);
            }
            // reduce the 8 row-groups (lanes differing in bits 3..5)
#pragma unroll
            for (int m = 8; m < 64; m <<= 1) {
#pragma unroll
                for (int q = 0; q < 8; q++) a[q] += __shfl_xor(a[q], m, 64);
            }
            if (rlane == 0) {
                // lane 'word' holds features word*8 .. word*8+7
                *(float4*)&s_agg[lc * 64 + word * 8 + 0] =
                    make_float4(a[0], a[1], a[2], a[3]);
                *(float4*)&s_agg[lc * 64 + word * 8 + 4] =
                    make_float4(a[4], a[5], a[6], a[7]);
            }
        }
#undef BF_LO
#undef BF_HI
    }
    __syncthreads();

    // phase B: mid[NCB][128] = relu(agg @ wo0 + bo0)
    {
        int j = tid & 127;
        int g = tid >> 7;
        float acc[16];
        float b = bo0[j];
#pragma unroll
        for (int c = 0; c < 16; c++) acc[c] = b;
        for (int k = 0; k < 64; k += 4) {
            float w0 = wo0[(k + 0) * 128 + j];
            float w1 = wo0[(k + 1) * 128 + j];
            float w2 = wo0[(k + 2) * 128 + j];
            float w3 = wo0[(k + 3) * 128 + j];
#pragma unroll
            for (int c = 0; c < 16; c++) {
                const float4 av = *(const float4*)&s_agg[(g * 16 + c) * 64 + k];
                acc[c] = fmaf(av.x, w0, acc[c]);
                acc[c] = fmaf(av.y, w1, acc[c]);
                acc[c] = fmaf(av.z, w2, acc[c]);
                acc[c] = fmaf(av.w, w3, acc[c]);
            }
        }
#pragma unroll
        for (int c = 0; c < 16; c++)
            s_mid[(g * 16 + c) * 128 + j] = fmaxf(acc[c], 0.f);
    }
    __syncthreads();

    // phase C: out[NCB][256] = relu(mid @ wo1 + bo1)
    {
        int m = tid;
        float acc[NCB];
        float b = bo1[m];
#pragma unroll
        for (int c = 0; c < NCB; c++) acc[c] = b;
        for (int j = 0; j < 128; j += 4) {
            float w0 = wo1[(j + 0) * 256 + m];
            float w1 = wo1[(j + 1) * 256 + m];
            float w2 = wo1[(j + 2) * 256 + m];
            float w3 = wo1[(j + 3) * 256 + m];
#pragma unroll
            for (int c = 0; c < NCB; c++) {
                const float4 mv = *(const float4*)&s_mid[c * 128 + j];
                acc[c] = fmaf(mv.x, w0, acc[c]);
                acc[c] = fmaf(mv.y, w1, acc[c]);
                acc[c] = fmaf(mv.z, w2, acc[c]);
                acc[c] = fmaf(mv.w, w3, acc[c]);
            }
        }
#pragma unroll
        for (int c = 0; c < NCB; c++)
            out[(size_t)(c0 + c) * 256 + m] = fmaxf(acc[c], 0.f);
    }
}

extern "C" void kernel_launch(void* const* d_in, const int* in_sizes, int n_in,
                              void* d_out, int out_size, void* d_ws, size_t ws_size,
                              hipStream_t stream)
{
    const float* pf      = (const float*)d_in[0];
    const int*   labels  = (const int*)d_in[1];
    const float* centers = (const float*)d_in[2];
    const float* points  = (const float*)d_in[3];
    const float* we0 = (const float*)d_in[4];
    const float* be0 = (const float*)d_in[5];
    const float* we1 = (const float*)d_in[6];
    const float* be1 = (const float*)d_in[7];
    const float* we2 = (const float*)d_in[8];
    const float* be2 = (const float*)d_in[9];
    const float* we3 = (const float*)d_in[10];
    const float* be3 = (const float*)d_in[11];
    const float* wa0 = (const float*)d_in[12];
    const float* ba0 = (const float*)d_in[13];
    const float* wa1 = (const float*)d_in[14];
    const float* ba1 = (const float*)d_in[15];
    const float* wo0 = (const float*)d_in[16];
    const float* bo0 = (const float*)d_in[17];
    const float* wo1 = (const float*)d_in[18];
    const float* bo1 = (const float*)d_in[19];
    float* out = (float*)d_out;

    int n = in_sizes[0] / 8;        // N points (2,000,000)
    int C = in_sizes[2] / 3;        // clusters (65,536)

    // workspace layout
    int* counts = (int*)d_ws;                   // C
    int* cursor = counts + C;                   // C
    int* off    = cursor + C;                   // C+1
    int* bsum   = off + C + 1;                  // <=256
    uintptr_t tb = ((uintptr_t)(bsum + 256) + 255) & ~(uintptr_t)255;
    unsigned short* tsort = (unsigned short*)tb; // n x 64 bf16, cluster-sorted

    hipMemsetAsync(counts, 0, (size_t)C * sizeof(int), stream);

    int pblocks = (n + TPB - 1) / TPB;
    int nb = (C + 255) / 256;                   // 256 scan blocks
    hist_kernel<<<pblocks, TPB, 0, stream>>>(labels, counts, n);
    scan_local<<<nb, 256, 0, stream>>>(counts, off, bsum, C);
    scan_base<<<1, 256, 0, stream>>>(bsum, off, nb, C);
    scan_apply<<<nb, 256, 0, stream>>>(off, cursor, bsum, C);

    point_mlp_kernel<<<pblocks, TPB, 0, stream>>>(
        pf, labels, centers, points,
        we0, be0, we1, be1, we2, be2, we3, be3,
        wa0, ba0, wa1, ba1, cursor, tsort, n);

    agg_outmlp_kernel<<<C / NCB, TPB, 0, stream>>>(
        tsort, off, wo0, bo0, wo1, bo1, out);
}

// Round 4
// 597.015 us; speedup vs baseline: 1.0449x; 1.0103x over previous
//
#include <hip/hip_runtime.h>
#include <hip/hip_bf16.h>
#include <math.h>
#include <stdint.h>

#define TPB 256
#define NCB 32   // clusters per agg block
#define SAGG_LD 68    // padded LDS stride for s_agg rows (64 + 4)
#define SMID_LD 132   // padded LDS stride for s_mid rows (128 + 4)

// ---------------------------------------------------------------------------
// Sort stage 1: histogram of labels
// ---------------------------------------------------------------------------
__global__ __launch_bounds__(TPB) void hist_kernel(
    const int* __restrict__ labels, int* __restrict__ counts, int n)
{
    int i = blockIdx.x * TPB + threadIdx.x;
    if (i < n) atomicAdd(&counts[labels[i]], 1);
}

// ---------------------------------------------------------------------------
// Parallel scan over C bins, 3 kernels:
//   S1: per-256-bin block: local exclusive scan -> off, block total -> bsum
//   S2: one block scans bsum (<=256 blocks) -> exclusive bases; off[C]=n
//   S3: off[i] += base[block]; cursor[i] = off[i]
// ---------------------------------------------------------------------------
__global__ __launch_bounds__(256) void scan_local(
    const int* __restrict__ counts, int* __restrict__ off,
    int* __restrict__ bsum, int C)
{
    __shared__ int sh[256];
    int t = threadIdx.x;
    int i = blockIdx.x * 256 + t;
    int v = (i < C) ? counts[i] : 0;
    sh[t] = v;
    __syncthreads();
    for (int d = 1; d < 256; d <<= 1) {
        int u = (t >= d) ? sh[t - d] : 0;
        __syncthreads();
        sh[t] += u;
        __syncthreads();
    }
    if (i < C) off[i] = sh[t] - v;          // local exclusive prefix
    if (t == 255) bsum[blockIdx.x] = sh[255];
}

__global__ __launch_bounds__(256) void scan_base(
    int* __restrict__ bsum, int* __restrict__ off, int nb, int C)
{
    __shared__ int sh[256];
    int t = threadIdx.x;
    int v = (t < nb) ? bsum[t] : 0;
    sh[t] = v;
    __syncthreads();
    for (int d = 1; d < 256; d <<= 1) {
        int u = (t >= d) ? sh[t - d] : 0;
        __syncthreads();
        sh[t] += u;
        __syncthreads();
    }
    if (t < nb) bsum[t] = sh[t] - v;        // exclusive base per block
    if (t == 255) off[C] = sh[255];         // total == n
}

__global__ __launch_bounds__(256) void scan_apply(
    int* __restrict__ off, int* __restrict__ cursor,
    const int* __restrict__ bsum, int C)
{
    int i = blockIdx.x * 256 + threadIdx.x;
    if (i < C) {
        int v = off[i] + bsum[blockIdx.x];
        off[i] = v;
        cursor[i] = v;
    }
}

// ---------------------------------------------------------------------------
// Stage 1: per-point MLP. Claims sorted slot via cursor atomic and writes the
// gated bf16 64-vector row at the sorted position (128B = 1 cacheline).
// (R1 note: launch_bounds(TPB,4) had zero effect - VGPR stayed 36; kept as
// harmless. Do not re-theorize spilling without disasm evidence.)
// ---------------------------------------------------------------------------
__global__ __launch_bounds__(TPB, 4) void point_mlp_kernel(
    const float* __restrict__ pf, const int* __restrict__ labels,
    const float* __restrict__ centers, const float* __restrict__ points,
    const float* __restrict__ we0, const float* __restrict__ be0,
    const float* __restrict__ we1, const float* __restrict__ be1,
    const float* __restrict__ we2, const float* __restrict__ be2,
    const float* __restrict__ we3, const float* __restrict__ be3,
    const float* __restrict__ wa0, const float* __restrict__ ba0,
    const float* __restrict__ wa1, const float* __restrict__ ba1,
    int* __restrict__ cursor, unsigned short* __restrict__ tsort, int n)
{
    int i = blockIdx.x * TPB + threadIdx.x;
    if (i >= n) return;

    float x[11];
    const float4* pf4 = (const float4*)pf;
    float4 p0 = pf4[(size_t)i * 2 + 0];
    float4 p1 = pf4[(size_t)i * 2 + 1];
    x[0] = p0.x; x[1] = p0.y; x[2] = p0.z; x[3] = p0.w;
    x[4] = p1.x; x[5] = p1.y; x[6] = p1.z; x[7] = p1.w;

    int lbl = labels[i];
    x[8]  = centers[lbl * 3 + 0] - points[(size_t)i * 3 + 0];
    x[9]  = centers[lbl * 3 + 1] - points[(size_t)i * 3 + 1];
    x[10] = centers[lbl * 3 + 2] - points[(size_t)i * 3 + 2];

    // claim sorted slot early; latency overlaps the MLP compute below
    int pos = atomicAdd(&cursor[lbl], 1);

    // attention MLP: 11 -> 64 relu -> 1 sigmoid
    float s = ba1[0];
#pragma unroll
    for (int j = 0; j < 64; j++) {
        float aj = ba0[j];
#pragma unroll
        for (int k = 0; k < 11; k++) aj = fmaf(x[k], wa0[k * 64 + j], aj);
        aj = fmaxf(aj, 0.f);
        s = fmaf(aj, wa1[j], s);
    }
    float gate = 1.f / (1.f + __expf(-s));

    // edge MLP: 11 -> 8 -> 16 -> 32
    float h1[8];
#pragma unroll
    for (int j = 0; j < 8; j++) {
        float v = be0[j];
#pragma unroll
        for (int k = 0; k < 11; k++) v = fmaf(x[k], we0[k * 8 + j], v);
        h1[j] = fmaxf(v, 0.f);
    }
    float h2[16];
#pragma unroll
    for (int j = 0; j < 16; j++) {
        float v = be1[j];
#pragma unroll
        for (int k = 0; k < 8; k++) v = fmaf(h1[k], we1[k * 16 + j], v);
        h2[j] = fmaxf(v, 0.f);
    }
    float h3[32];
#pragma unroll
    for (int j = 0; j < 32; j++) {
        float v = be2[j];
#pragma unroll
        for (int k = 0; k < 16; k++) v = fmaf(h2[k], we2[k * 32 + j], v);
        h3[j] = fmaxf(v, 0.f);
    }

    // final layer 32 -> 64, relu, gate, pack bf16, store row at sorted pos
    uint4* dst = (uint4*)(tsort + (size_t)pos * 64);
#pragma unroll
    for (int g = 0; g < 8; g++) {
        unsigned int w[4];
#pragma unroll
        for (int q = 0; q < 4; q++) {
            unsigned int packed = 0;
#pragma unroll
            for (int h = 0; h < 2; h++) {
                int j = g * 8 + q * 2 + h;
                float v = be3[j];
#pragma unroll
                for (int k = 0; k < 32; k++) v = fmaf(h3[k], we3[k * 64 + j], v);
                v = fmaxf(v, 0.f) * gate;
                __hip_bfloat16 b = __float2bfloat16(v);
                unsigned short us = *(unsigned short*)&b;
                packed |= ((unsigned int)us) << (16 * h);
            }
            w[q] = packed;
        }
        dst[g] = make_uint4(w[0], w[1], w[2], w[3]);
    }
}

// ---------------------------------------------------------------------------
// Stage 2: aggregation + output MLP.
// R3 change (phases B/C): register-blocked GEMM mapping. Old code read LDS
// via wave-uniform broadcast (1024 ds_read_b128/thread in C, 16B useful per
// instr -> ~12K LDS-pipe cyc/wave, est ~160us chip-wide). New mapping:
//   B: thread = 2 clusters x 8 outs ->  32 A-reads/thread, distinct rows
//   C: thread = 4 clusters x 8 outs -> 128 A-reads/thread, distinct rows
// LDS strides padded (68/132 floats) so concurrent row-reads hit distinct
// banks; float4 alignment preserved (272B/528B are 16B multiples).
// ---------------------------------------------------------------------------
__global__ __launch_bounds__(TPB) void agg_outmlp_kernel(
    const unsigned short* __restrict__ tsort,
    const int* __restrict__ off,
    const float* __restrict__ wo0, const float* __restrict__ bo0,
    const float* __restrict__ wo1, const float* __restrict__ bo1,
    float* __restrict__ out)
{
    __shared__ float s_agg[NCB * SAGG_LD];   // ~8.7 KB
    __shared__ float s_mid[NCB * SMID_LD];   // ~16.9 KB
    int tid = threadIdx.x;
    int c0 = blockIdx.x * NCB;

    // phase A: aggregate (R2 version, stride updated)
    {
        int lane  = tid & 63;
        int w     = tid >> 6;
        int rlane = lane >> 3;           // 0..7 : which row of the 8-row group
        int word  = lane & 7;            // 0..7 : uint4 index within 128B row
        const uint4* t128 = (const uint4*)tsort;   // one row = 8 x uint4
#define BF_LO(u) (__uint_as_float((u) << 16))
#define BF_HI(u) (__uint_as_float((u) & 0xffff0000u))
        for (int lc = w * 8; lc < w * 8 + 8; lc++) {
            int rb = off[c0 + lc];
            int re = off[c0 + lc + 1];
            float a[8];
#pragma unroll
            for (int q = 0; q < 8; q++) a[q] = 0.f;
            for (int r = rb; r < re; r += 16) {
                int r0 = r + rlane;
                int r1 = r + 8 + rlane;
                uint4 v0 = make_uint4(0u, 0u, 0u, 0u);
                uint4 v1 = make_uint4(0u, 0u, 0u, 0u);
                if (r0 < re) v0 = t128[(size_t)r0 * 8 + word];
                if (r1 < re) v1 = t128[(size_t)r1 * 8 + word];
                a[0] += BF_LO(v0.x) + BF_LO(v1.x);
                a[1] += BF_HI(v0.x) + BF_HI(v1.x);
                a[2] += BF_LO(v0.y) + BF_LO(v1.y);
                a[3] += BF_HI(v0.y) + BF_HI(v1.y);
                a[4] += BF_LO(v0.z) + BF_LO(v1.z);
                a[5] += BF_HI(v0.z) + BF_HI(v1.z);
                a[6] += BF_LO(v0.w) + BF_LO(v1.w);
                a[7] += BF_HI(v0.w) + BF_HI(v1.w);
            }
            // reduce the 8 row-groups (lanes differing in bits 3..5)
#pragma unroll
            for (int m = 8; m < 64; m <<= 1) {
#pragma unroll
                for (int q = 0; q < 8; q++) a[q] += __shfl_xor(a[q], m, 64);
            }
            if (rlane == 0) {
                // lane 'word' holds features word*8 .. word*8+7
                *(float4*)&s_agg[lc * SAGG_LD + word * 8 + 0] =
                    make_float4(a[0], a[1], a[2], a[3]);
                *(float4*)&s_agg[lc * SAGG_LD + word * 8 + 4] =
                    make_float4(a[4], a[5], a[6], a[7]);
            }
        }
#undef BF_LO
#undef BF_HI
    }
    __syncthreads();

    // phase B: mid[NCB][128] = relu(agg @ wo0 + bo0)
    // thread t: mg = t&15 -> outputs m0..m0+7; cg = t>>4 -> clusters cg*2+{0,1}
    {
        int mg = tid & 15;
        int cg = tid >> 4;
        int m0 = mg * 8;
        float acc[2][8];
#pragma unroll
        for (int mi = 0; mi < 8; mi++) {
            float b = bo0[m0 + mi];
            acc[0][mi] = b;
            acc[1][mi] = b;
        }
        for (int k = 0; k < 64; k += 4) {
            float4 a0 = *(const float4*)&s_agg[(cg * 2 + 0) * SAGG_LD + k];
            float4 a1 = *(const float4*)&s_agg[(cg * 2 + 1) * SAGG_LD + k];
            float av0[4] = {a0.x, a0.y, a0.z, a0.w};
            float av1[4] = {a1.x, a1.y, a1.z, a1.w};
#pragma unroll
            for (int q = 0; q < 4; q++) {
                float4 wlo = *(const float4*)&wo0[(k + q) * 128 + m0];
                float4 whi = *(const float4*)&wo0[(k + q) * 128 + m0 + 4];
                float wv[8] = {wlo.x, wlo.y, wlo.z, wlo.w,
                               whi.x, whi.y, whi.z, whi.w};
#pragma unroll
                for (int mi = 0; mi < 8; mi++) {
                    acc[0][mi] = fmaf(av0[q], wv[mi], acc[0][mi]);
                    acc[1][mi] = fmaf(av1[q], wv[mi], acc[1][mi]);
                }
            }
        }
#pragma unroll
        for (int c = 0; c < 2; c++) {
            float4 lo = make_float4(fmaxf(acc[c][0], 0.f), fmaxf(acc[c][1], 0.f),
                                    fmaxf(acc[c][2], 0.f), fmaxf(acc[c][3], 0.f));
            float4 hi = make_float4(fmaxf(acc[c][4], 0.f), fmaxf(acc[c][5], 0.f),
                                    fmaxf(acc[c][6], 0.f), fmaxf(acc[c][7], 0.f));
            *(float4*)&s_mid[(cg * 2 + c) * SMID_LD + m0 + 0] = lo;
            *(float4*)&s_mid[(cg * 2 + c) * SMID_LD + m0 + 4] = hi;
        }
    }
    __syncthreads();

    // phase C: out[NCB][256] = relu(mid @ wo1 + bo1)
    // thread t: mg = t&31 -> outputs m0..m0+7; cg = t>>5 -> clusters cg*4+{0..3}
    {
        int mg = tid & 31;
        int cg = tid >> 5;
        int m0 = mg * 8;
        float acc[4][8];
#pragma unroll
        for (int mi = 0; mi < 8; mi++) {
            float b = bo1[m0 + mi];
            acc[0][mi] = b;
            acc[1][mi] = b;
            acc[2][mi] = b;
            acc[3][mi] = b;
        }
        for (int j = 0; j < 128; j += 4) {
            float4 a0 = *(const float4*)&s_mid[(cg * 4 + 0) * SMID_LD + j];
            float4 a1 = *(const float4*)&s_mid[(cg * 4 + 1) * SMID_LD + j];
            float4 a2 = *(const float4*)&s_mid[(cg * 4 + 2) * SMID_LD + j];
            float4 a3 = *(const float4*)&s_mid[(cg * 4 + 3) * SMID_LD + j];
            float av0[4] = {a0.x, a0.y, a0.z, a0.w};
            float av1[4] = {a1.x, a1.y, a1.z, a1.w};
            float av2[4] = {a2.x, a2.y, a2.z, a2.w};
            float av3[4] = {a3.x, a3.y, a3.z, a3.w};
#pragma unroll
            for (int q = 0; q < 4; q++) {
                float4 wlo = *(const float4*)&wo1[(j + q) * 256 + m0];
                float4 whi = *(const float4*)&wo1[(j + q) * 256 + m0 + 4];
                float wv[8] = {wlo.x, wlo.y, wlo.z, wlo.w,
                               whi.x, whi.y, whi.z, whi.w};
#pragma unroll
                for (int mi = 0; mi < 8; mi++) {
                    acc[0][mi] = fmaf(av0[q], wv[mi], acc[0][mi]);
                    acc[1][mi] = fmaf(av1[q], wv[mi], acc[1][mi]);
                    acc[2][mi] = fmaf(av2[q], wv[mi], acc[2][mi]);
                    acc[3][mi] = fmaf(av3[q], wv[mi], acc[3][mi]);
                }
            }
        }
#pragma unroll
        for (int c = 0; c < 4; c++) {
            float4 lo = make_float4(fmaxf(acc[c][0], 0.f), fmaxf(acc[c][1], 0.f),
                                    fmaxf(acc[c][2], 0.f), fmaxf(acc[c][3], 0.f));
            float4 hi = make_float4(fmaxf(acc[c][4], 0.f), fmaxf(acc[c][5], 0.f),
                                    fmaxf(acc[c][6], 0.f), fmaxf(acc[c][7], 0.f));
            size_t row = (size_t)(c0 + cg * 4 + c) * 256 + m0;
            *(float4*)&out[row + 0] = lo;
            *(float4*)&out[row + 4] = hi;
        }
    }
}

extern "C" void kernel_launch(void* const* d_in, const int* in_sizes, int n_in,
                              void* d_out, int out_size, void* d_ws, size_t ws_size,
                              hipStream_t stream)
{
    const float* pf      = (const float*)d_in[0];
    const int*   labels  = (const int*)d_in[1];
    const float* centers = (const float*)d_in[2];
    const float* points  = (const float*)d_in[3];
    const float* we0 = (const float*)d_in[4];
    const float* be0 = (const float*)d_in[5];
    const float* we1 = (const float*)d_in[6];
    const float* be1 = (const float*)d_in[7];
    const float* we2 = (const float*)d_in[8];
    const float* be2 = (const float*)d_in[9];
    const float* we3 = (const float*)d_in[10];
    const float* be3 = (const float*)d_in[11];
    const float* wa0 = (const float*)d_in[12];
    const float* ba0 = (const float*)d_in[13];
    const float* wa1 = (const float*)d_in[14];
    const float* ba1 = (const float*)d_in[15];
    const float* wo0 = (const float*)d_in[16];
    const float* bo0 = (const float*)d_in[17];
    const float* wo1 = (const float*)d_in[18];
    const float* bo1 = (const float*)d_in[19];
    float* out = (float*)d_out;

    int n = in_sizes[0] / 8;        // N points (2,000,000)
    int C = in_sizes[2] / 3;        // clusters (65,536)

    // workspace layout
    int* counts = (int*)d_ws;                   // C
    int* cursor = counts + C;                   // C
    int* off    = cursor + C;                   // C+1
    int* bsum   = off + C + 1;                  // <=256
    uintptr_t tb = ((uintptr_t)(bsum + 256) + 255) & ~(uintptr_t)255;
    unsigned short* tsort = (unsigned short*)tb; // n x 64 bf16, cluster-sorted

    hipMemsetAsync(counts, 0, (size_t)C * sizeof(int), stream);

    int pblocks = (n + TPB - 1) / TPB;
    int nb = (C + 255) / 256;                   // 256 scan blocks
    hist_kernel<<<pblocks, TPB, 0, stream>>>(labels, counts, n);
    scan_local<<<nb, 256, 0, stream>>>(counts, off, bsum, C);
    scan_base<<<1, 256, 0, stream>>>(bsum, off, nb, C);
    scan_apply<<<nb, 256, 0, stream>>>(off, cursor, bsum, C);

    point_mlp_kernel<<<pblocks, TPB, 0, stream>>>(
        pf, labels, centers, points,
        we0, be0, we1, be1, we2, be2, we3, be3,
        wa0, ba0, wa1, ba1, cursor, tsort, n);

    agg_outmlp_kernel<<<C / NCB, TPB, 0, stream>>>(
        tsort, off, wo0, bo0, wo1, bo1, out);
}

// Round 5
// 557.523 us; speedup vs baseline: 1.1189x; 1.0708x over previous
//
#include <hip/hip_runtime.h>
#include <hip/hip_bf16.h>
#include <math.h>
#include <stdint.h>

#define TPB 256
#define NCB 32   // clusters per agg block
#define SAGG_LD 68    // padded LDS stride for s_agg rows (64 + 4)
#define SMID_LD 132   // padded LDS stride for s_mid rows (128 + 4)

typedef float f32x4 __attribute__((ext_vector_type(4)));
typedef short bf16x8 __attribute__((ext_vector_type(8)));

__device__ inline unsigned int bf16bits(float f)
{
    __hip_bfloat16 b = __float2bfloat16(f);
    return (unsigned int)(*(unsigned short*)&b);
}

// ---------------------------------------------------------------------------
// Sort stage 1: histogram of labels
// ---------------------------------------------------------------------------
__global__ __launch_bounds__(TPB) void hist_kernel(
    const int* __restrict__ labels, int* __restrict__ counts, int n)
{
    int i = blockIdx.x * TPB + threadIdx.x;
    if (i < n) atomicAdd(&counts[labels[i]], 1);
}

// ---------------------------------------------------------------------------
// Parallel scan over C bins, 3 kernels.
// ---------------------------------------------------------------------------
__global__ __launch_bounds__(256) void scan_local(
    const int* __restrict__ counts, int* __restrict__ off,
    int* __restrict__ bsum, int C)
{
    __shared__ int sh[256];
    int t = threadIdx.x;
    int i = blockIdx.x * 256 + t;
    int v = (i < C) ? counts[i] : 0;
    sh[t] = v;
    __syncthreads();
    for (int d = 1; d < 256; d <<= 1) {
        int u = (t >= d) ? sh[t - d] : 0;
        __syncthreads();
        sh[t] += u;
        __syncthreads();
    }
    if (i < C) off[i] = sh[t] - v;          // local exclusive prefix
    if (t == 255) bsum[blockIdx.x] = sh[255];
}

__global__ __launch_bounds__(256) void scan_base(
    int* __restrict__ bsum, int* __restrict__ off, int nb, int C)
{
    __shared__ int sh[256];
    int t = threadIdx.x;
    int v = (t < nb) ? bsum[t] : 0;
    sh[t] = v;
    __syncthreads();
    for (int d = 1; d < 256; d <<= 1) {
        int u = (t >= d) ? sh[t - d] : 0;
        __syncthreads();
        sh[t] += u;
        __syncthreads();
    }
    if (t < nb) bsum[t] = sh[t] - v;        // exclusive base per block
    if (t == 255) off[C] = sh[255];         // total == n
}

__global__ __launch_bounds__(256) void scan_apply(
    int* __restrict__ off, int* __restrict__ cursor,
    const int* __restrict__ bsum, int C)
{
    int i = blockIdx.x * 256 + threadIdx.x;
    if (i < C) {
        int v = off[i] + bsum[blockIdx.x];
        off[i] = v;
        cursor[i] = v;
    }
}

// ---------------------------------------------------------------------------
// Stage 1: per-point MLP.
// R4 change: final layer (32->64, 2048 FMA/pt = 43% of VALU instrs) moved to
// MFMA. Orientation D[j][pt] = we3^T @ h3^T per 64-point wave batch:
//   A (weights)  : lane l elem i = we3[((l>>4)*8+i)*64 + mt*16 + (l&15)]
//   B (points)   : staged in LDS [16 kk][64 pt] bf16-pairs; lane l dword ii
//                  = s_h3[(l>>4)*4+ii][nt*16+(l&15)]   (k=(l>>4)*8+i, n=l&15)
//   D            : row j = mt*16+(l>>4)*4+q, col pt = nt*16+(l&15)  [m89]
// gate/pos reach D-layout via __shfl; stores are 8B uint2 of 4 consecutive j.
// No barrier needed: per-wave LDS region, same-wave DS ops execute in order.
// Early-return removed (MFMA is a full-wave op); tail lanes clamp loads and
// skip atomic/store.
// ---------------------------------------------------------------------------
__global__ __launch_bounds__(TPB, 4) void point_mlp_kernel(
    const float* __restrict__ pf, const int* __restrict__ labels,
    const float* __restrict__ centers, const float* __restrict__ points,
    const float* __restrict__ we0, const float* __restrict__ be0,
    const float* __restrict__ we1, const float* __restrict__ be1,
    const float* __restrict__ we2, const float* __restrict__ be2,
    const float* __restrict__ we3, const float* __restrict__ be3,
    const float* __restrict__ wa0, const float* __restrict__ ba0,
    const float* __restrict__ wa1, const float* __restrict__ ba1,
    int* __restrict__ cursor, unsigned short* __restrict__ tsort, int n)
{
    __shared__ unsigned int s_h3[4][16][64];   // 16KB: [wave][kk][pt-in-wave]

    int i0 = blockIdx.x * TPB + threadIdx.x;
    int i  = (i0 < n) ? i0 : (n - 1);          // clamp: tail lanes compute junk

    float x[11];
    const float4* pf4 = (const float4*)pf;
    float4 p0 = pf4[(size_t)i * 2 + 0];
    float4 p1 = pf4[(size_t)i * 2 + 1];
    x[0] = p0.x; x[1] = p0.y; x[2] = p0.z; x[3] = p0.w;
    x[4] = p1.x; x[5] = p1.y; x[6] = p1.z; x[7] = p1.w;

    int lbl = labels[i];
    x[8]  = centers[lbl * 3 + 0] - points[(size_t)i * 3 + 0];
    x[9]  = centers[lbl * 3 + 1] - points[(size_t)i * 3 + 1];
    x[10] = centers[lbl * 3 + 2] - points[(size_t)i * 3 + 2];

    // claim sorted slot early; latency overlaps the MLP compute below
    int pos = 0;
    if (i0 < n) pos = atomicAdd(&cursor[lbl], 1);

    // attention MLP: 11 -> 64 relu -> 1 sigmoid (unchanged, per-thread VALU)
    float s = ba1[0];
#pragma unroll
    for (int j = 0; j < 64; j++) {
        float aj = ba0[j];
#pragma unroll
        for (int k = 0; k < 11; k++) aj = fmaf(x[k], wa0[k * 64 + j], aj);
        aj = fmaxf(aj, 0.f);
        s = fmaf(aj, wa1[j], s);
    }
    float gate = 1.f / (1.f + __expf(-s));

    // edge MLP: 11 -> 8 -> 16 -> 32 (unchanged, per-thread VALU)
    float h1[8];
#pragma unroll
    for (int j = 0; j < 8; j++) {
        float v = be0[j];
#pragma unroll
        for (int k = 0; k < 11; k++) v = fmaf(x[k], we0[k * 8 + j], v);
        h1[j] = fmaxf(v, 0.f);
    }
    float h2[16];
#pragma unroll
    for (int j = 0; j < 16; j++) {
        float v = be1[j];
#pragma unroll
        for (int k = 0; k < 8; k++) v = fmaf(h1[k], we1[k * 16 + j], v);
        h2[j] = fmaxf(v, 0.f);
    }
    float h3[32];
#pragma unroll
    for (int j = 0; j < 32; j++) {
        float v = be2[j];
#pragma unroll
        for (int k = 0; k < 16; k++) v = fmaf(h2[k], we2[k * 32 + j], v);
        h3[j] = fmaxf(v, 0.f);
    }

    // ---- L3 via MFMA ----
    int lane = threadIdx.x & 63;
    int w    = threadIdx.x >> 6;
    int lg   = lane >> 4;     // 0..3
    int lm   = lane & 15;     // 0..15
    int pbase = blockIdx.x * TPB + w * 64;   // first point of this wave

    // stage own h3 as bf16 pairs: s_h3[w][kk][lane] = (h3[2kk], h3[2kk+1])
#pragma unroll
    for (int kk = 0; kk < 16; kk++) {
        s_h3[w][kk][lane] = bf16bits(h3[2 * kk]) | (bf16bits(h3[2 * kk + 1]) << 16);
    }

    // A-fragments (weights), one per M-tile of 16 j's
    bf16x8 afrag[4];
#pragma unroll
    for (int mt = 0; mt < 4; mt++) {
        union { unsigned int u[4]; bf16x8 v; } au;
#pragma unroll
        for (int ii = 0; ii < 4; ii++) {
            float w0 = we3[(lg * 8 + 2 * ii + 0) * 64 + mt * 16 + lm];
            float w1 = we3[(lg * 8 + 2 * ii + 1) * 64 + mt * 16 + lm];
            au.u[ii] = bf16bits(w0) | (bf16bits(w1) << 16);
        }
        afrag[mt] = au.v;
    }

#pragma unroll
    for (int nt = 0; nt < 4; nt++) {
        int   spt  = nt * 16 + lm;                 // source point-in-wave
        float g    = __shfl(gate, spt, 64);
        int   ppos = __shfl(pos,  spt, 64);
        bool  valid = (pbase + spt) < n;

        union { unsigned int u[4]; bf16x8 v; } bu;
#pragma unroll
        for (int ii = 0; ii < 4; ii++) bu.u[ii] = s_h3[w][lg * 4 + ii][spt];

#pragma unroll
        for (int mt = 0; mt < 4; mt++) {
            f32x4 acc = {0.f, 0.f, 0.f, 0.f};
            acc = __builtin_amdgcn_mfma_f32_16x16x32_bf16(afrag[mt], bu.v, acc, 0, 0, 0);
            int jb = mt * 16 + lg * 4;
            const float4 bias = *(const float4*)&be3[jb];
            float v0 = fmaxf(acc[0] + bias.x, 0.f) * g;
            float v1 = fmaxf(acc[1] + bias.y, 0.f) * g;
            float v2 = fmaxf(acc[2] + bias.z, 0.f) * g;
            float v3 = fmaxf(acc[3] + bias.w, 0.f) * g;
            if (valid) {
                unsigned int d0 = bf16bits(v0) | (bf16bits(v1) << 16);
                unsigned int d1 = bf16bits(v2) | (bf16bits(v3) << 16);
                *(uint2*)((unsigned int*)tsort + (size_t)ppos * 32 + (jb >> 1)) =
                    make_uint2(d0, d1);
            }
        }
    }
}

// ---------------------------------------------------------------------------
// Stage 2: aggregation + output MLP (unchanged from R3).
// ---------------------------------------------------------------------------
__global__ __launch_bounds__(TPB) void agg_outmlp_kernel(
    const unsigned short* __restrict__ tsort,
    const int* __restrict__ off,
    const float* __restrict__ wo0, const float* __restrict__ bo0,
    const float* __restrict__ wo1, const float* __restrict__ bo1,
    float* __restrict__ out)
{
    __shared__ float s_agg[NCB * SAGG_LD];   // ~8.7 KB
    __shared__ float s_mid[NCB * SMID_LD];   // ~16.9 KB
    int tid = threadIdx.x;
    int c0 = blockIdx.x * NCB;

    // phase A: aggregate
    {
        int lane  = tid & 63;
        int w     = tid >> 6;
        int rlane = lane >> 3;           // 0..7 : which row of the 8-row group
        int word  = lane & 7;            // 0..7 : uint4 index within 128B row
        const uint4* t128 = (const uint4*)tsort;   // one row = 8 x uint4
#define BF_LO(u) (__uint_as_float((u) << 16))
#define BF_HI(u) (__uint_as_float((u) & 0xffff0000u))
        for (int lc = w * 8; lc < w * 8 + 8; lc++) {
            int rb = off[c0 + lc];
            int re = off[c0 + lc + 1];
            float a[8];
#pragma unroll
            for (int q = 0; q < 8; q++) a[q] = 0.f;
            for (int r = rb; r < re; r += 16) {
                int r0 = r + rlane;
                int r1 = r + 8 + rlane;
                uint4 v0 = make_uint4(0u, 0u, 0u, 0u);
                uint4 v1 = make_uint4(0u, 0u, 0u, 0u);
                if (r0 < re) v0 = t128[(size_t)r0 * 8 + word];
                if (r1 < re) v1 = t128[(size_t)r1 * 8 + word];
                a[0] += BF_LO(v0.x) + BF_LO(v1.x);
                a[1] += BF_HI(v0.x) + BF_HI(v1.x);
                a[2] += BF_LO(v0.y) + BF_LO(v1.y);
                a[3] += BF_HI(v0.y) + BF_HI(v1.y);
                a[4] += BF_LO(v0.z) + BF_LO(v1.z);
                a[5] += BF_HI(v0.z) + BF_HI(v1.z);
                a[6] += BF_LO(v0.w) + BF_LO(v1.w);
                a[7] += BF_HI(v0.w) + BF_HI(v1.w);
            }
            // reduce the 8 row-groups (lanes differing in bits 3..5)
#pragma unroll
            for (int m = 8; m < 64; m <<= 1) {
#pragma unroll
                for (int q = 0; q < 8; q++) a[q] += __shfl_xor(a[q], m, 64);
            }
            if (rlane == 0) {
                // lane 'word' holds features word*8 .. word*8+7
                *(float4*)&s_agg[lc * SAGG_LD + word * 8 + 0] =
                    make_float4(a[0], a[1], a[2], a[3]);
                *(float4*)&s_agg[lc * SAGG_LD + word * 8 + 4] =
                    make_float4(a[4], a[5], a[6], a[7]);
            }
        }
#undef BF_LO
#undef BF_HI
    }
    __syncthreads();

    // phase B: mid[NCB][128] = relu(agg @ wo0 + bo0)
    {
        int mg = tid & 15;
        int cg = tid >> 4;
        int m0 = mg * 8;
        float acc[2][8];
#pragma unroll
        for (int mi = 0; mi < 8; mi++) {
            float b = bo0[m0 + mi];
            acc[0][mi] = b;
            acc[1][mi] = b;
        }
        for (int k = 0; k < 64; k += 4) {
            float4 a0 = *(const float4*)&s_agg[(cg * 2 + 0) * SAGG_LD + k];
            float4 a1 = *(const float4*)&s_agg[(cg * 2 + 1) * SAGG_LD + k];
            float av0[4] = {a0.x, a0.y, a0.z, a0.w};
            float av1[4] = {a1.x, a1.y, a1.z, a1.w};
#pragma unroll
            for (int q = 0; q < 4; q++) {
                float4 wlo = *(const float4*)&wo0[(k + q) * 128 + m0];
                float4 whi = *(const float4*)&wo0[(k + q) * 128 + m0 + 4];
                float wv[8] = {wlo.x, wlo.y, wlo.z, wlo.w,
                               whi.x, whi.y, whi.z, whi.w};
#pragma unroll
                for (int mi = 0; mi < 8; mi++) {
                    acc[0][mi] = fmaf(av0[q], wv[mi], acc[0][mi]);
                    acc[1][mi] = fmaf(av1[q], wv[mi], acc[1][mi]);
                }
            }
        }
#pragma unroll
        for (int c = 0; c < 2; c++) {
            float4 lo = make_float4(fmaxf(acc[c][0], 0.f), fmaxf(acc[c][1], 0.f),
                                    fmaxf(acc[c][2], 0.f), fmaxf(acc[c][3], 0.f));
            float4 hi = make_float4(fmaxf(acc[c][4], 0.f), fmaxf(acc[c][5], 0.f),
                                    fmaxf(acc[c][6], 0.f), fmaxf(acc[c][7], 0.f));
            *(float4*)&s_mid[(cg * 2 + c) * SMID_LD + m0 + 0] = lo;
            *(float4*)&s_mid[(cg * 2 + c) * SMID_LD + m0 + 4] = hi;
        }
    }
    __syncthreads();

    // phase C: out[NCB][256] = relu(mid @ wo1 + bo1)
    {
        int mg = tid & 31;
        int cg = tid >> 5;
        int m0 = mg * 8;
        float acc[4][8];
#pragma unroll
        for (int mi = 0; mi < 8; mi++) {
            float b = bo1[m0 + mi];
            acc[0][mi] = b;
            acc[1][mi] = b;
            acc[2][mi] = b;
            acc[3][mi] = b;
        }
        for (int j = 0; j < 128; j += 4) {
            float4 a0 = *(const float4*)&s_mid[(cg * 4 + 0) * SMID_LD + j];
            float4 a1 = *(const float4*)&s_mid[(cg * 4 + 1) * SMID_LD + j];
            float4 a2 = *(const float4*)&s_mid[(cg * 4 + 2) * SMID_LD + j];
            float4 a3 = *(const float4*)&s_mid[(cg * 4 + 3) * SMID_LD + j];
            float av0[4] = {a0.x, a0.y, a0.z, a0.w};
            float av1[4] = {a1.x, a1.y, a1.z, a1.w};
            float av2[4] = {a2.x, a2.y, a2.z, a2.w};
            float av3[4] = {a3.x, a3.y, a3.z, a3.w};
#pragma unroll
            for (int q = 0; q < 4; q++) {
                float4 wlo = *(const float4*)&wo1[(j + q) * 256 + m0];
                float4 whi = *(const float4*)&wo1[(j + q) * 256 + m0 + 4];
                float wv[8] = {wlo.x, wlo.y, wlo.z, wlo.w,
                               whi.x, whi.y, whi.z, whi.w};
#pragma unroll
                for (int mi = 0; mi < 8; mi++) {
                    acc[0][mi] = fmaf(av0[q], wv[mi], acc[0][mi]);
                    acc[1][mi] = fmaf(av1[q], wv[mi], acc[1][mi]);
                    acc[2][mi] = fmaf(av2[q], wv[mi], acc[2][mi]);
                    acc[3][mi] = fmaf(av3[q], wv[mi], acc[3][mi]);
                }
            }
        }
#pragma unroll
        for (int c = 0; c < 4; c++) {
            float4 lo = make_float4(fmaxf(acc[c][0], 0.f), fmaxf(acc[c][1], 0.f),
                                    fmaxf(acc[c][2], 0.f), fmaxf(acc[c][3], 0.f));
            float4 hi = make_float4(fmaxf(acc[c][4], 0.f), fmaxf(acc[c][5], 0.f),
                                    fmaxf(acc[c][6], 0.f), fmaxf(acc[c][7], 0.f));
            size_t row = (size_t)(c0 + cg * 4 + c) * 256 + m0;
            *(float4*)&out[row + 0] = lo;
            *(float4*)&out[row + 4] = hi;
        }
    }
}

extern "C" void kernel_launch(void* const* d_in, const int* in_sizes, int n_in,
                              void* d_out, int out_size, void* d_ws, size_t ws_size,
                              hipStream_t stream)
{
    const float* pf      = (const float*)d_in[0];
    const int*   labels  = (const int*)d_in[1];
    const float* centers = (const float*)d_in[2];
    const float* points  = (const float*)d_in[3];
    const float* we0 = (const float*)d_in[4];
    const float* be0 = (const float*)d_in[5];
    const float* we1 = (const float*)d_in[6];
    const float* be1 = (const float*)d_in[7];
    const float* we2 = (const float*)d_in[8];
    const float* be2 = (const float*)d_in[9];
    const float* we3 = (const float*)d_in[10];
    const float* be3 = (const float*)d_in[11];
    const float* wa0 = (const float*)d_in[12];
    const float* ba0 = (const float*)d_in[13];
    const float* wa1 = (const float*)d_in[14];
    const float* ba1 = (const float*)d_in[15];
    const float* wo0 = (const float*)d_in[16];
    const float* bo0 = (const float*)d_in[17];
    const float* wo1 = (const float*)d_in[18];
    const float* bo1 = (const float*)d_in[19];
    float* out = (float*)d_out;

    int n = in_sizes[0] / 8;        // N points (2,000,000)
    int C = in_sizes[2] / 3;        // clusters (65,536)

    // workspace layout
    int* counts = (int*)d_ws;                   // C
    int* cursor = counts + C;                   // C
    int* off    = cursor + C;                   // C+1
    int* bsum   = off + C + 1;                  // <=256
    uintptr_t tb = ((uintptr_t)(bsum + 256) + 255) & ~(uintptr_t)255;
    unsigned short* tsort = (unsigned short*)tb; // n x 64 bf16, cluster-sorted

    hipMemsetAsync(counts, 0, (size_t)C * sizeof(int), stream);

    int pblocks = (n + TPB - 1) / TPB;
    int nb = (C + 255) / 256;                   // 256 scan blocks
    hist_kernel<<<pblocks, TPB, 0, stream>>>(labels, counts, n);
    scan_local<<<nb, 256, 0, stream>>>(counts, off, bsum, C);
    scan_base<<<1, 256, 0, stream>>>(bsum, off, nb, C);
    scan_apply<<<nb, 256, 0, stream>>>(off, cursor, bsum, C);

    point_mlp_kernel<<<pblocks, TPB, 0, stream>>>(
        pf, labels, centers, points,
        we0, be0, we1, be1, we2, be2, we3, be3,
        wa0, ba0, wa1, ba1, cursor, tsort, n);

    agg_outmlp_kernel<<<C / NCB, TPB, 0, stream>>>(
        tsort, off, wo0, bo0, wo1, bo1, out);
}